// Round 1
// baseline (568.872 us; speedup 1.0000x reference)
//
#include <hip/hip_runtime.h>

#define NF 64  // feature dim for both GCN layers

// ---------------- degree / normalization ----------------

__global__ void init_deg(float* __restrict__ deg, int n) {
    int i = blockIdx.x * blockDim.x + threadIdx.x;
    if (i < n) deg[i] = 1.0f;  // self-loop contributes 1
}

__global__ void count_deg(const int* __restrict__ dst, float* __restrict__ deg, int E) {
    int e = blockIdx.x * blockDim.x + threadIdx.x;
    if (e < E) atomicAdd(&deg[dst[e]], 1.0f);
}

__global__ void compute_dinv(float* __restrict__ deg, int n) {
    int i = blockIdx.x * blockDim.x + threadIdx.x;
    if (i < n) deg[i] = rsqrtf(deg[i]);  // deg >= 1 always (self-loops)
}

// ---------------- dense GEMM: out[n,64] = (relu?)in[n,64] @ W[64,64] ----------------

template <bool RELU_IN>
__global__ __launch_bounds__(256) void gemm_n64(const float* __restrict__ in,
                                                const float* __restrict__ W,
                                                float* __restrict__ out, int n) {
    __shared__ float Wl[64][64];   // 16 KB; read Wl[k][j], lane j -> 2 lanes/bank (free)
    __shared__ float rowl[4][64];
    int tid = threadIdx.x;
    for (int i = tid; i < 64 * 64; i += 256) Wl[i >> 6][i & 63] = W[i];

    int r = tid >> 6;        // row within block (0..3)
    int j = tid & 63;        // output column
    int row = blockIdx.x * 4 + r;
    float x = 0.0f;
    if (row < n) {
        x = in[row * NF + j];
        if (RELU_IN) x = fmaxf(x, 0.0f);
    }
    rowl[r][j] = x;
    __syncthreads();
    if (row >= n) return;

    float acc = 0.0f;
#pragma unroll
    for (int k = 0; k < 64; ++k) acc += rowl[r][k] * Wl[k][j];  // rowl broadcast, Wl conflict-free
    out[row * NF + j] = acc;
}

// ---------------- accumulator init: self-loop message + bias ----------------

__global__ void init_accum(const float* __restrict__ h, const float* __restrict__ dinv,
                           const float* __restrict__ b, float* __restrict__ acc, int n) {
    int t = blockIdx.x * blockDim.x + threadIdx.x;
    if (t >= n * NF) return;
    int i = t >> 6, f = t & 63;
    float d = dinv[i];
    acc[t] = h[t] * d * d + b[f];
}

// ---------------- edge scatter: acc[dst] += h[src] * dinv[src]*dinv[dst] ----------------

__global__ __launch_bounds__(256) void edge_msg(const int* __restrict__ src,
                                                const int* __restrict__ dst,
                                                const float* __restrict__ dinv,
                                                const float* __restrict__ h,
                                                float* __restrict__ acc, int E) {
    int t = blockIdx.x * blockDim.x + threadIdx.x;
    int lane = t & 63;
    int wid = t >> 6;
    int nw = (gridDim.x * blockDim.x) >> 6;
    for (int e = wid; e < E; e += nw) {
        int s = src[e], d = dst[e];
        float nrm = dinv[s] * dinv[d];            // wave-uniform scalar loads
        float v = h[s * NF + lane] * nrm;         // coalesced 256B row gather
        atomicAdd(&acc[d * NF + lane], v);        // coalesced 256B row scatter-add
    }
}

// ---------------- decoder: pred = relu(relu(acc2) @ Wd1 + bd1) @ Wd2 + bd2 ----------------

__global__ __launch_bounds__(256) void decoder(const float* __restrict__ acc2,
                                               const float* __restrict__ Wd1,
                                               const float* __restrict__ bd1,
                                               const float* __restrict__ Wd2,
                                               const float* __restrict__ bd2,
                                               float* __restrict__ pred, int n) {
    __shared__ float W1l[64][32];  // 8 KB
    __shared__ float w2l[32];
    __shared__ float b1l[32];
    int tid = threadIdx.x;
    for (int i = tid; i < 64 * 32; i += 256) W1l[i >> 5][i & 31] = Wd1[i];
    if (tid < 32) { w2l[tid] = Wd2[tid]; b1l[tid] = bd1[tid]; }
    __syncthreads();

    int lane = tid & 63;
    int row = blockIdx.x * 4 + (tid >> 6);
    if (row >= n) return;

    int j = lane & 31;       // hidden unit
    int half = lane >> 5;    // k-range split: lanes j and j+32 share hidden j
    float s = 0.0f;
#pragma unroll
    for (int k = 0; k < 32; ++k) {
        int kk = half * 32 + k;
        float x = fmaxf(acc2[row * NF + kk], 0.0f);  // broadcast per half-wave
        s += x * W1l[kk][j];                          // conflict-free (2 lanes/bank)
    }
    s += __shfl_xor(s, 32);                           // combine k-halves
    float hj = fmaxf(s + b1l[j], 0.0f);
    float p = hj * w2l[j];
#pragma unroll
    for (int m = 16; m >= 1; m >>= 1) p += __shfl_xor(p, m);  // sum over 32 hidden
    if (lane == 0) pred[row] = p + bd2[0];
}

// ---------------- host launcher ----------------

extern "C" void kernel_launch(void* const* d_in, const int* in_sizes, int n_in,
                              void* d_out, int out_size, void* d_ws, size_t ws_size,
                              hipStream_t stream) {
    const float* x   = (const float*)d_in[0];
    const int*   ei  = (const int*)d_in[1];     // (2,E) int32 (jax x64 disabled)
    const float* W1  = (const float*)d_in[2];
    const float* b1  = (const float*)d_in[3];
    const float* W2  = (const float*)d_in[4];
    const float* b2  = (const float*)d_in[5];
    const float* Wd1 = (const float*)d_in[6];
    const float* bd1 = (const float*)d_in[7];
    const float* Wd2 = (const float*)d_in[8];
    const float* bd2 = (const float*)d_in[9];
    float* pred = (float*)d_out;

    const int N = in_sizes[0] / NF;
    const int E = in_sizes[1] / 2;
    const int* src = ei;
    const int* dst = ei + E;

    // workspace layout
    char* ws = (char*)d_ws;
    float* dinv = (float*)ws;                              // N floats (deg -> dinv in place)
    float* h    = (float*)(ws + ((size_t)N * 4 + 255 & ~255ull));
    float* acc  = h + (size_t)N * NF;

    const int B = 256;
    // normalization
    init_deg<<<(N + B - 1) / B, B, 0, stream>>>(dinv, N);
    count_deg<<<(E + B - 1) / B, B, 0, stream>>>(dst, dinv, E);
    compute_dinv<<<(N + B - 1) / B, B, 0, stream>>>(dinv, N);

    const int gemm_blocks = (N + 3) / 4;
    const int pw_blocks   = (N * NF + B - 1) / B;
    const int edge_blocks = 2048;  // grid-stride, ~8 blocks/CU co-resident

    // layer 1: h = x @ W1 ; acc = selfloop + b1 ; scatter edges
    gemm_n64<false><<<gemm_blocks, B, 0, stream>>>(x, W1, h, N);
    init_accum<<<pw_blocks, B, 0, stream>>>(h, dinv, b1, acc, N);
    edge_msg<<<edge_blocks, B, 0, stream>>>(src, dst, dinv, h, acc, E);

    // layer 2: h = relu(acc) @ W2 ; acc = selfloop + b2 ; scatter edges
    gemm_n64<true><<<gemm_blocks, B, 0, stream>>>(acc, W2, h, N);
    init_accum<<<pw_blocks, B, 0, stream>>>(h, dinv, b2, acc, N);
    edge_msg<<<edge_blocks, B, 0, stream>>>(src, dst, dinv, h, acc, E);

    // decoder (relu fused on load)
    decoder<<<gemm_blocks, B, 0, stream>>>(acc, Wd1, bd1, Wd2, bd2, pred, N);
}

// Round 2
// 439.060 us; speedup vs baseline: 1.2957x; 1.2957x over previous
//
#include <hip/hip_runtime.h>

#define NF 64  // feature dim for both GCN layers

// ---------------- CSR build ----------------

__global__ void count_deg(const int* __restrict__ dst, int* __restrict__ cnt, int E) {
    int e = blockIdx.x * blockDim.x + threadIdx.x;
    if (e < E) atomicAdd(&cnt[dst[e]], 1);
}

// single-block exclusive scan: rowptr[0..n], rowptr[n] = total
__global__ __launch_bounds__(1024) void scan_rowptr(const int* __restrict__ cnt,
                                                    int* __restrict__ rowptr, int n) {
    __shared__ int wsum[16];
    __shared__ int wexcl[16];
    __shared__ int carry_s;
    int tid = threadIdx.x, lane = tid & 63, w = tid >> 6;
    if (tid == 0) carry_s = 0;
    __syncthreads();
    for (int base = 0; base < n; base += 1024) {
        int i = base + tid;
        int v = (i < n) ? cnt[i] : 0;
        int inc = v;  // inclusive scan within wave
#pragma unroll
        for (int d = 1; d < 64; d <<= 1) {
            int t = __shfl_up(inc, d);
            if (lane >= d) inc += t;
        }
        if (lane == 63) wsum[w] = inc;
        __syncthreads();
        if (w == 0 && lane < 16) {
            int s = wsum[lane];
            int e2 = s;
#pragma unroll
            for (int d = 1; d < 16; d <<= 1) {
                int t = __shfl_up(e2, d);
                if (lane >= d) e2 += t;
            }
            wexcl[lane] = e2 - s;  // exclusive wave base
        }
        __syncthreads();
        int carry = carry_s;
        int excl = carry + wexcl[w] + inc - v;
        if (i < n) rowptr[i] = excl;
        if (i == n - 1) rowptr[n] = excl + v;
        __syncthreads();
        if (tid == 1023) carry_s = carry + wexcl[15] + wsum[15];
        __syncthreads();
    }
}

__global__ void dinv_fill(const int* __restrict__ cnt, float* __restrict__ dinv,
                          int* __restrict__ fill, int n) {
    int i = blockIdx.x * blockDim.x + threadIdx.x;
    if (i < n) {
        dinv[i] = rsqrtf((float)(cnt[i] + 1));  // +1 self-loop
        fill[i] = 0;
    }
}

__global__ void fill_csr(const int* __restrict__ src, const int* __restrict__ dst,
                         const int* __restrict__ rowptr, int* __restrict__ fill,
                         const float* __restrict__ dinv, int2* __restrict__ pairs, int E) {
    int e = blockIdx.x * blockDim.x + threadIdx.x;
    if (e >= E) return;
    int d = dst[e], s = src[e];
    int pos = rowptr[d] + atomicAdd(&fill[d], 1);
    pairs[pos] = make_int2(s, __float_as_int(dinv[s]));
}

// ---------------- dense GEMM: out[n,64] = (relu?)in[n,64] @ W[64,64] ----------------
// 16 rows/block: W staged once per 16 rows (4x less LDS-staging traffic than R0)

template <bool RELU_IN>
__global__ __launch_bounds__(256) void gemm_n64(const float* __restrict__ in,
                                                const float* __restrict__ W,
                                                float* __restrict__ out, int n) {
    __shared__ float Wl[64][64];     // Wl[k][j]: lane j -> 2 lanes/bank (free)
    __shared__ float rowl[16][64];   // broadcast reads (free)
    int tid = threadIdx.x;
    for (int idx = tid; idx < 4096; idx += 256) Wl[idx >> 6][idx & 63] = W[idx];
    int base = blockIdx.x * 16;
    for (int idx = tid; idx < 1024; idx += 256) {
        int r = idx >> 6, c = idx & 63;
        int row = base + r;
        float x = (row < n) ? in[row * NF + c] : 0.0f;
        if (RELU_IN) x = fmaxf(x, 0.0f);
        rowl[r][c] = x;
    }
    __syncthreads();
    int j = tid & 63, w = tid >> 6;
    int r0 = w * 4;
    float a0 = 0.f, a1 = 0.f, a2 = 0.f, a3 = 0.f;
#pragma unroll
    for (int k = 0; k < 64; ++k) {
        float wk = Wl[k][j];
        a0 += rowl[r0 + 0][k] * wk;
        a1 += rowl[r0 + 1][k] * wk;
        a2 += rowl[r0 + 2][k] * wk;
        a3 += rowl[r0 + 3][k] * wk;
    }
    int row = base + r0;
    if (row + 0 < n) out[(row + 0) * NF + j] = a0;
    if (row + 1 < n) out[(row + 1) * NF + j] = a1;
    if (row + 2 < n) out[(row + 2) * NF + j] = a2;
    if (row + 3 < n) out[(row + 3) * NF + j] = a3;
}

// ---------------- per-node gather aggregation (no atomics) ----------------
// acc[i] = h[i]*dinv[i]^2 + b + sum_{(s->i)} h[s] * dinv[s]*dinv[i]

__global__ __launch_bounds__(256) void gather_nbr(const int2* __restrict__ pairs,
                                                  const int* __restrict__ rowptr,
                                                  const float* __restrict__ dinv,
                                                  const float* __restrict__ h,
                                                  const float* __restrict__ b,
                                                  float* __restrict__ acc, int n) {
    int tid = threadIdx.x, lane = tid & 63;
    int i = blockIdx.x * 4 + (tid >> 6);  // wave per node
    if (i >= n) return;
    float di = dinv[i];
    float a = h[(size_t)i * NF + lane] * di * di + b[lane];
    int j = rowptr[i], end = rowptr[i + 1];
    for (; j + 1 < end; j += 2) {  // 2x unroll for ILP on the row gathers
        int2 p0 = pairs[j], p1 = pairs[j + 1];
        float w0 = __int_as_float(p0.y) * di;
        float w1 = __int_as_float(p1.y) * di;
        a += h[(size_t)p0.x * NF + lane] * w0;
        a += h[(size_t)p1.x * NF + lane] * w1;
    }
    if (j < end) {
        int2 p = pairs[j];
        a += h[(size_t)p.x * NF + lane] * (__int_as_float(p.y) * di);
    }
    acc[(size_t)i * NF + lane] = a;
}

// ---------------- decoder: pred = relu(relu(acc2) @ Wd1 + bd1) @ Wd2 + bd2 ----------------

__global__ __launch_bounds__(256) void decoder(const float* __restrict__ acc2,
                                               const float* __restrict__ Wd1,
                                               const float* __restrict__ bd1,
                                               const float* __restrict__ Wd2,
                                               const float* __restrict__ bd2,
                                               float* __restrict__ pred, int n) {
    __shared__ float W1l[64][32];
    __shared__ float w2l[32];
    __shared__ float b1l[32];
    int tid = threadIdx.x;
    for (int i = tid; i < 2048; i += 256) W1l[i >> 5][i & 31] = Wd1[i];
    if (tid < 32) { w2l[tid] = Wd2[tid]; b1l[tid] = bd1[tid]; }
    __syncthreads();

    int lane = tid & 63;
    int jj = lane & 31;      // hidden unit
    int half = lane >> 5;    // k-range split
    int rbase = blockIdx.x * 16 + (tid >> 6) * 4;
    for (int rr = 0; rr < 4; ++rr) {
        int row = rbase + rr;
        if (row >= n) return;
        float s = 0.0f;
#pragma unroll
        for (int k = 0; k < 32; ++k) {
            int kk = half * 32 + k;
            s += fmaxf(acc2[row * NF + kk], 0.0f) * W1l[kk][jj];
        }
        s += __shfl_xor(s, 32);
        float hj = fmaxf(s + b1l[jj], 0.0f);
        float p = hj * w2l[jj];
#pragma unroll
        for (int m = 16; m >= 1; m >>= 1) p += __shfl_xor(p, m);
        if (lane == 0) pred[row] = p + bd2[0];
    }
}

// ---------------- host launcher ----------------

extern "C" void kernel_launch(void* const* d_in, const int* in_sizes, int n_in,
                              void* d_out, int out_size, void* d_ws, size_t ws_size,
                              hipStream_t stream) {
    const float* x   = (const float*)d_in[0];
    const int*   ei  = (const int*)d_in[1];
    const float* W1  = (const float*)d_in[2];
    const float* b1  = (const float*)d_in[3];
    const float* W2  = (const float*)d_in[4];
    const float* b2  = (const float*)d_in[5];
    const float* Wd1 = (const float*)d_in[6];
    const float* bd1 = (const float*)d_in[7];
    const float* Wd2 = (const float*)d_in[8];
    const float* bd2 = (const float*)d_in[9];
    float* pred = (float*)d_out;

    const int N = in_sizes[0] / NF;
    const int E = in_sizes[1] / 2;
    const int* src = ei;
    const int* dst = ei + E;

    // workspace layout (all 8B-aligned chunks)
    char* ws = (char*)d_ws;
    size_t off = 0;
    int*   cnt    = (int*)(ws + off);  off += (size_t)4 * N;
    int*   rowptr = (int*)(ws + off);  off += (size_t)4 * (N + 1);
    int*   fill   = (int*)(ws + off);  off += (size_t)4 * N;
    float* dinv   = (float*)(ws + off); off += (size_t)4 * N;
    off = (off + 7) & ~(size_t)7;
    int2*  pairs  = (int2*)(ws + off); off += (size_t)8 * E;
    float* h      = (float*)(ws + off); off += (size_t)4 * N * NF;
    float* acc    = (float*)(ws + off);

    const int B = 256;
    const int eb = (E + B - 1) / B;
    const int nb = (N + B - 1) / B;

    // CSR build (by dst) + dinv
    hipMemsetAsync(cnt, 0, (size_t)4 * N, stream);
    count_deg<<<eb, B, 0, stream>>>(dst, cnt, E);
    scan_rowptr<<<1, 1024, 0, stream>>>(cnt, rowptr, N);
    dinv_fill<<<nb, B, 0, stream>>>(cnt, dinv, fill, N);
    fill_csr<<<eb, B, 0, stream>>>(src, dst, rowptr, fill, dinv, pairs, E);

    const int gemm_blocks   = (N + 15) / 16;
    const int gather_blocks = (N + 3) / 4;

    // layer 1
    gemm_n64<false><<<gemm_blocks, B, 0, stream>>>(x, W1, h, N);
    gather_nbr<<<gather_blocks, B, 0, stream>>>(pairs, rowptr, dinv, h, b1, acc, N);
    // layer 2
    gemm_n64<true><<<gemm_blocks, B, 0, stream>>>(acc, W2, h, N);
    gather_nbr<<<gather_blocks, B, 0, stream>>>(pairs, rowptr, dinv, h, b2, acc, N);
    // decoder
    decoder<<<gemm_blocks, B, 0, stream>>>(acc, Wd1, bd1, Wd2, bd2, pred, N);
}

// Round 3
// 346.366 us; speedup vs baseline: 1.6424x; 1.2676x over previous
//
#include <hip/hip_runtime.h>

#define NF 64  // feature dim for both GCN layers

__device__ __forceinline__ float rlf(float v, int l) {
    return __int_as_float(__builtin_amdgcn_readlane(__float_as_int(v), l));
}

// ---------------- CSR build ----------------

__global__ void count_deg(const int* __restrict__ dst, int* __restrict__ cnt, int E) {
    int e = blockIdx.x * blockDim.x + threadIdx.x;
    if (e < E) atomicAdd(&cnt[dst[e]], 1);
}

// single-block exclusive scan: rowptr[0..n], rowptr[n] = total
__global__ __launch_bounds__(1024) void scan_rowptr(const int* __restrict__ cnt,
                                                    int* __restrict__ rowptr, int n) {
    __shared__ int wsum[16];
    __shared__ int wexcl[16];
    __shared__ int carry_s;
    int tid = threadIdx.x, lane = tid & 63, w = tid >> 6;
    if (tid == 0) carry_s = 0;
    __syncthreads();
    for (int base = 0; base < n; base += 1024) {
        int i = base + tid;
        int v = (i < n) ? cnt[i] : 0;
        int inc = v;  // inclusive scan within wave
#pragma unroll
        for (int d = 1; d < 64; d <<= 1) {
            int t = __shfl_up(inc, d);
            if (lane >= d) inc += t;
        }
        if (lane == 63) wsum[w] = inc;
        __syncthreads();
        if (w == 0 && lane < 16) {
            int s = wsum[lane];
            int e2 = s;
#pragma unroll
            for (int d = 1; d < 16; d <<= 1) {
                int t = __shfl_up(e2, d);
                if (lane >= d) e2 += t;
            }
            wexcl[lane] = e2 - s;  // exclusive wave base
        }
        __syncthreads();
        int carry = carry_s;
        int excl = carry + wexcl[w] + inc - v;
        if (i < n) rowptr[i] = excl;
        if (i == n - 1) rowptr[n] = excl + v;
        __syncthreads();
        if (tid == 1023) carry_s = carry + wexcl[15] + wsum[15];
        __syncthreads();
    }
}

__global__ void dinv_fill(const int* __restrict__ cnt, float* __restrict__ dinv,
                          int* __restrict__ fill, int n) {
    int i = blockIdx.x * blockDim.x + threadIdx.x;
    if (i < n) {
        dinv[i] = rsqrtf((float)(cnt[i] + 1));  // +1 self-loop
        fill[i] = 0;
    }
}

__global__ void fill_csr(const int* __restrict__ src, const int* __restrict__ dst,
                         const int* __restrict__ rowptr, int* __restrict__ fill,
                         const float* __restrict__ dinv, int2* __restrict__ pairs, int E) {
    int e = blockIdx.x * blockDim.x + threadIdx.x;
    if (e >= E) return;
    int d = dst[e], s = src[e];
    int pos = rowptr[d] + atomicAdd(&fill[d], 1);
    pairs[pos] = make_int2(s, __float_as_int(dinv[s]));
}

// ---------------- fused gather + transform (+ decoder) ----------------
// layer math:  out = relu( agg(xin) @ W + b )   with agg = D^-1/2 A D^-1/2 incl self-loop
// (agg(x)@W == agg(x@W): aggregation and transform commute — both linear)
// wave per node; W column `lane` held in 64 VGPRs; a_k broadcast via v_readlane.

template <bool DEC>
__global__ __launch_bounds__(256) void gcn_layer(
    const int2* __restrict__ pairs, const int* __restrict__ rowptr,
    const float* __restrict__ dinv, const float* __restrict__ xin,
    const float* __restrict__ W, const float* __restrict__ bias,
    float* __restrict__ xout,
    const float* __restrict__ Wd1, const float* __restrict__ bd1,
    const float* __restrict__ Wd2, const float* __restrict__ bd2,
    float* __restrict__ pred, int n)
{
    __shared__ float Wd1l[64][32];  // decoder W1; [k][j] -> bank j, 2 lanes/addr = free
    __shared__ float bd1l[32];
    __shared__ float w2l[32];
    int tid = threadIdx.x;
    int lane = tid & 63;
    if (DEC) {
        for (int i = tid; i < 2048; i += 256) Wd1l[i >> 5][i & 31] = Wd1[i];
        if (tid < 32) { bd1l[tid] = bd1[tid]; w2l[tid] = Wd2[tid]; }
    }
    __syncthreads();

    // stage W column `lane` into registers (64 coalesced 256B loads, L2-hot)
    float wcol[64];
#pragma unroll
    for (int k = 0; k < 64; ++k) wcol[k] = W[k * NF + lane];
    float bv = bias[lane];
    float bd2v = DEC ? bd2[0] : 0.0f;

    int wid = blockIdx.x * 4 + (tid >> 6);
    int nw = gridDim.x * 4;
    for (int i = wid; i < n; i += nw) {
        float di = dinv[i];
        float a = xin[(size_t)i * NF + lane] * di * di;  // self-loop message

        int jb = __builtin_amdgcn_readfirstlane(rowptr[i]);
        int je = __builtin_amdgcn_readfirstlane(rowptr[i + 1]);
        for (int base = jb; base < je; base += 64) {
            int cnt = min(64, je - base);
            int2 p = make_int2(0, 0);
            if (base + lane < je) p = pairs[base + lane];  // whole edge list in lanes
            int e = 0;
            for (; e + 3 < cnt; e += 4) {  // 4 gathers in flight
                int s0 = __builtin_amdgcn_readlane(p.x, e);
                int s1 = __builtin_amdgcn_readlane(p.x, e + 1);
                int s2 = __builtin_amdgcn_readlane(p.x, e + 2);
                int s3 = __builtin_amdgcn_readlane(p.x, e + 3);
                float w0 = __int_as_float(__builtin_amdgcn_readlane(p.y, e)) * di;
                float w1 = __int_as_float(__builtin_amdgcn_readlane(p.y, e + 1)) * di;
                float w2 = __int_as_float(__builtin_amdgcn_readlane(p.y, e + 2)) * di;
                float w3 = __int_as_float(__builtin_amdgcn_readlane(p.y, e + 3)) * di;
                float v0 = xin[(size_t)s0 * NF + lane];
                float v1 = xin[(size_t)s1 * NF + lane];
                float v2 = xin[(size_t)s2 * NF + lane];
                float v3 = xin[(size_t)s3 * NF + lane];
                a = fmaf(v0, w0, a);
                a = fmaf(v1, w1, a);
                a = fmaf(v2, w2, a);
                a = fmaf(v3, w3, a);
            }
            for (; e < cnt; ++e) {
                int s0 = __builtin_amdgcn_readlane(p.x, e);
                float w0 = __int_as_float(__builtin_amdgcn_readlane(p.y, e)) * di;
                a = fmaf(xin[(size_t)s0 * NF + lane], w0, a);
            }
        }

        // transform: o[lane] = relu( sum_k a_k * W[k][lane] + b[lane] )
        float o = bv;
#pragma unroll
        for (int k = 0; k < 64; ++k) o = fmaf(rlf(a, k), wcol[k], o);
        o = fmaxf(o, 0.0f);

        if (!DEC) {
            xout[(size_t)i * NF + lane] = o;
        } else {
            // decoder: pred[i] = relu(o @ Wd1 + bd1) @ Wd2 + bd2
            // each lane computes full 64-sum for hidden j = lane&31 (halves redundant)
            int j = lane & 31;
            float s = 0.0f;
#pragma unroll
            for (int k = 0; k < 64; ++k) s = fmaf(rlf(o, k), Wd1l[k][j], s);
            float hj = fmaxf(s + bd1l[j], 0.0f);
            float pp = hj * w2l[j];
#pragma unroll
            for (int m = 16; m >= 1; m >>= 1) pp += __shfl_xor(pp, m);  // sum j=0..31
            if (lane == 0) pred[i] = pp + bd2v;
        }
    }
}

// ---------------- host launcher ----------------

extern "C" void kernel_launch(void* const* d_in, const int* in_sizes, int n_in,
                              void* d_out, int out_size, void* d_ws, size_t ws_size,
                              hipStream_t stream) {
    const float* x   = (const float*)d_in[0];
    const int*   ei  = (const int*)d_in[1];
    const float* W1  = (const float*)d_in[2];
    const float* b1  = (const float*)d_in[3];
    const float* W2  = (const float*)d_in[4];
    const float* b2  = (const float*)d_in[5];
    const float* Wd1 = (const float*)d_in[6];
    const float* bd1 = (const float*)d_in[7];
    const float* Wd2 = (const float*)d_in[8];
    const float* bd2 = (const float*)d_in[9];
    float* pred = (float*)d_out;

    const int N = in_sizes[0] / NF;
    const int E = in_sizes[1] / 2;
    const int* src = ei;
    const int* dst = ei + E;

    // workspace layout
    char* ws = (char*)d_ws;
    size_t off = 0;
    int*   cnt    = (int*)(ws + off);   off += (size_t)4 * N;
    int*   rowptr = (int*)(ws + off);   off += (size_t)4 * (N + 1);
    int*   fill   = (int*)(ws + off);   off += (size_t)4 * N;
    float* dinv   = (float*)(ws + off); off += (size_t)4 * N;
    off = (off + 7) & ~(size_t)7;
    int2*  pairs  = (int2*)(ws + off);  off += (size_t)8 * E;
    float* h1     = (float*)(ws + off);

    const int B = 256;
    const int eb = (E + B - 1) / B;
    const int nb = (N + B - 1) / B;

    // CSR build (by dst) + dinv
    hipMemsetAsync(cnt, 0, (size_t)4 * N, stream);
    count_deg<<<eb, B, 0, stream>>>(dst, cnt, E);
    scan_rowptr<<<1, 1024, 0, stream>>>(cnt, rowptr, N);
    dinv_fill<<<nb, B, 0, stream>>>(cnt, dinv, fill, N);
    fill_csr<<<eb, B, 0, stream>>>(src, dst, rowptr, fill, dinv, pairs, E);

    const int gb = 1536;  // ~6 blocks/CU; waves grid-stride over nodes

    // layer 1: h1 = relu( agg(x) @ W1 + b1 )
    gcn_layer<false><<<gb, B, 0, stream>>>(pairs, rowptr, dinv, x, W1, b1, h1,
                                           Wd1, bd1, Wd2, bd2, pred, N);
    // layer 2 + decoder: pred = relu(relu(agg(h1)@W2+b2)@Wd1+bd1)@Wd2+bd2
    gcn_layer<true><<<gb, B, 0, stream>>>(pairs, rowptr, dinv, h1, W2, b2, h1,
                                          Wd1, bd1, Wd2, bd2, pred, N);
}

// Round 5
// 280.356 us; speedup vs baseline: 2.0291x; 1.2354x over previous
//
#include <hip/hip_runtime.h>

#define NF 64  // feature dim for both GCN layers

__device__ __forceinline__ float rlf(float v, int l) {
    return __int_as_float(__builtin_amdgcn_readlane(__float_as_int(v), l));
}

// ---------------- CSR build ----------------

__global__ void count_deg(const int* __restrict__ dst, int* __restrict__ cnt, int E) {
    int e = blockIdx.x * blockDim.x + threadIdx.x;
    if (e < E) atomicAdd(&cnt[dst[e]], 1);
}

// pass 1: block-local exclusive scan (1024 elems/block) + block sums
__global__ __launch_bounds__(1024) void scan_blk(const int* __restrict__ cnt,
                                                 int* __restrict__ rowptr,
                                                 int* __restrict__ bsum, int n) {
    __shared__ int wsum[16];
    __shared__ int wexcl[16];
    int tid = threadIdx.x, lane = tid & 63, w = tid >> 6;
    int i = blockIdx.x * 1024 + tid;
    int v = (i < n) ? cnt[i] : 0;
    int inc = v;
#pragma unroll
    for (int d = 1; d < 64; d <<= 1) {
        int t = __shfl_up(inc, d);
        if (lane >= d) inc += t;
    }
    if (lane == 63) wsum[w] = inc;
    __syncthreads();
    if (w == 0 && lane < 16) {
        int s = wsum[lane];
        int e2 = s;
#pragma unroll
        for (int d = 1; d < 16; d <<= 1) {
            int t = __shfl_up(e2, d);
            if (lane >= d) e2 += t;
        }
        wexcl[lane] = e2 - s;
    }
    __syncthreads();
    if (i < n) rowptr[i] = wexcl[w] + inc - v;
    if (tid == 1023) bsum[blockIdx.x] = wexcl[15] + wsum[15];
}

// pass 2: single-block exclusive scan of block sums (nb <= 1024)
__global__ __launch_bounds__(1024) void scan_part(int* __restrict__ bsum, int nb) {
    __shared__ int wsum[16];
    __shared__ int wexcl[16];
    int tid = threadIdx.x, lane = tid & 63, w = tid >> 6;
    int v = (tid < nb) ? bsum[tid] : 0;
    int inc = v;
#pragma unroll
    for (int d = 1; d < 64; d <<= 1) {
        int t = __shfl_up(inc, d);
        if (lane >= d) inc += t;
    }
    if (lane == 63) wsum[w] = inc;
    __syncthreads();
    if (w == 0 && lane < 16) {
        int s = wsum[lane];
        int e2 = s;
#pragma unroll
        for (int d = 1; d < 16; d <<= 1) {
            int t = __shfl_up(e2, d);
            if (lane >= d) e2 += t;
        }
        wexcl[lane] = e2 - s;
    }
    __syncthreads();
    if (tid < nb) bsum[tid] = wexcl[w] + inc - v;
}

// pass 3: add block offsets; write rowptr[n]; also dinv + fill init (fused)
__global__ void scan_add(int* __restrict__ rowptr, const int* __restrict__ bsum,
                         const int* __restrict__ cnt, float* __restrict__ dinv,
                         int* __restrict__ fill, int n) {
    int i = blockIdx.x * blockDim.x + threadIdx.x;
    if (i < n) {
        int c = cnt[i];
        int r = rowptr[i] + bsum[i >> 10];
        rowptr[i] = r;
        if (i == n - 1) rowptr[n] = r + c;
        dinv[i] = rsqrtf((float)(c + 1));  // +1 self-loop
        fill[i] = 0;
    }
}

__global__ void fill_csr(const int* __restrict__ src, const int* __restrict__ dst,
                         const int* __restrict__ rowptr, int* __restrict__ fill,
                         const float* __restrict__ dinv, int2* __restrict__ pairs, int E) {
    int e = blockIdx.x * blockDim.x + threadIdx.x;
    if (e >= E) return;
    int d = dst[e], s = src[e];
    int pos = rowptr[d] + atomicAdd(&fill[d], 1);
    pairs[pos] = make_int2(s, __float_as_int(dinv[s]));
}

// ---------------- fused gather + transform (+ decoder) ----------------
// out = relu( agg(xin) @ W + b );  agg and transform commute (both linear).
// Wave per node. Gather layout: 16 lanes x float4 per row, so ONE dwordx4
// wave-load fetches FOUR edges' rows (one per 16-lane quarter). Edge idx and
// weight broadcast to quarters via __shfl (bpermute). Quarter partials are
// butterfly-reduced; transform is a fully-unrolled readlane matvec.

template <bool DEC>
__global__ __launch_bounds__(256) void gcn_layer(
    const int2* __restrict__ pairs, const int* __restrict__ rowptr,
    const float* __restrict__ dinv, const float* __restrict__ xin,
    const float* __restrict__ W, const float* __restrict__ bias,
    float* __restrict__ xout,
    const float* __restrict__ Wd1, const float* __restrict__ bd1,
    const float* __restrict__ Wd2, const float* __restrict__ bd2,
    float* __restrict__ pred, int n)
{
    __shared__ float Wd1l[64][32];  // [k][j]: bank j, 2 lanes/addr = free
    __shared__ float bd1l[32];
    __shared__ float w2l[32];
    int tid = threadIdx.x;
    int lane = tid & 63;
    if (DEC) {
        for (int i = tid; i < 2048; i += 256) Wd1l[i >> 5][i & 31] = Wd1[i];
        if (tid < 32) { bd1l[tid] = bd1[tid]; w2l[tid] = Wd2[tid]; }
    }
    __syncthreads();

    // W column `lane` in registers
    float wcol[64];
#pragma unroll
    for (int k = 0; k < 64; ++k) wcol[k] = W[k * NF + lane];
    float bv = bias[lane];
    float bd2v = DEC ? bd2[0] : 0.0f;

    int q = lane >> 4;          // quarter (which edge of a 4-edge round)
    int fl = (lane & 15) * 4;   // feature base handled by this lane

    int wid = blockIdx.x * 4 + (tid >> 6);
    int nw = gridDim.x * 4;
    for (int i = wid; i < n; i += nw) {
        float di = dinv[i];
        int jb = __builtin_amdgcn_readfirstlane(rowptr[i]);
        int je = __builtin_amdgcn_readfirstlane(rowptr[i + 1]);

        // self-loop message: only quarter 0 contributes (others weight 0)
        float4 sv = *reinterpret_cast<const float4*>(xin + (size_t)i * NF + fl);
        float wself = (q == 0) ? di * di : 0.0f;
        float a[4];
        a[0] = sv.x * wself; a[1] = sv.y * wself;
        a[2] = sv.z * wself; a[3] = sv.w * wself;

        for (int base = jb; base < je; base += 64) {
            int cnt = min(64, je - base);
            int2 p = make_int2(0, 0);   // default: src 0, weight bits 0 -> +0.0
            if (base + lane < je) p = pairs[base + lane];
            for (int e = 0; e < cnt; e += 4) {
                int sl = e + q;                                   // <= 63 always
                int s = __shfl(p.x, sl);                          // per-quarter edge
                float wgt = __int_as_float(__shfl(p.y, sl)) * di; // 0 for tail lanes
                float4 v = *reinterpret_cast<const float4*>(xin + (size_t)s * NF + fl);
                a[0] = fmaf(v.x, wgt, a[0]);
                a[1] = fmaf(v.y, wgt, a[1]);
                a[2] = fmaf(v.z, wgt, a[2]);
                a[3] = fmaf(v.w, wgt, a[3]);
            }
        }
        // reduce across quarters: all lanes end with full sums
#pragma unroll
        for (int j = 0; j < 4; ++j) {
            a[j] += __shfl_xor(a[j], 16);
            a[j] += __shfl_xor(a[j], 32);
        }

        // transform: o[lane] = relu( sum_k a_k * W[k][lane] + b[lane] )
        // feature k lives in component k&3 of lane k>>2 (static under unroll)
        float o = bv;
#pragma unroll
        for (int k = 0; k < 64; ++k) o = fmaf(rlf(a[k & 3], k >> 2), wcol[k], o);
        o = fmaxf(o, 0.0f);

        if (!DEC) {
            xout[(size_t)i * NF + lane] = o;
        } else {
            int j = lane & 31;
            float s = 0.0f;
#pragma unroll
            for (int k = 0; k < 64; ++k) s = fmaf(rlf(o, k), Wd1l[k][j], s);
            float hj = fmaxf(s + bd1l[j], 0.0f);
            float pp = hj * w2l[j];
#pragma unroll
            for (int m = 16; m >= 1; m >>= 1) pp += __shfl_xor(pp, m);
            if (lane == 0) pred[i] = pp + bd2v;
        }
    }
}

// ---------------- host launcher ----------------

extern "C" void kernel_launch(void* const* d_in, const int* in_sizes, int n_in,
                              void* d_out, int out_size, void* d_ws, size_t ws_size,
                              hipStream_t stream) {
    const float* x   = (const float*)d_in[0];
    const int*   ei  = (const int*)d_in[1];
    const float* W1  = (const float*)d_in[2];
    const float* b1  = (const float*)d_in[3];
    const float* W2  = (const float*)d_in[4];
    const float* b2  = (const float*)d_in[5];
    const float* Wd1 = (const float*)d_in[6];
    const float* bd1 = (const float*)d_in[7];
    const float* Wd2 = (const float*)d_in[8];
    const float* bd2 = (const float*)d_in[9];
    float* pred = (float*)d_out;

    const int N = in_sizes[0] / NF;
    const int E = in_sizes[1] / 2;
    const int* src = ei;
    const int* dst = ei + E;

    // workspace layout
    char* ws = (char*)d_ws;
    size_t off = 0;
    int*   cnt    = (int*)(ws + off);   off += (size_t)4 * N;
    int*   rowptr = (int*)(ws + off);   off += (size_t)4 * (N + 1);
    int*   fill   = (int*)(ws + off);   off += (size_t)4 * N;
    float* dinv   = (float*)(ws + off); off += (size_t)4 * N;
    int*   bsum   = (int*)(ws + off);   off += (size_t)4 * 1024;
    off = (off + 15) & ~(size_t)15;
    int2*  pairs  = (int2*)(ws + off);  off += (size_t)8 * E;
    float* h1     = (float*)(ws + off);

    const int B = 256;
    const int eb = (E + B - 1) / B;
    const int nb = (N + B - 1) / B;
    const int nb1024 = (N + 1023) / 1024;

    // CSR build (by dst) + dinv
    hipMemsetAsync(cnt, 0, (size_t)4 * N, stream);
    count_deg<<<eb, B, 0, stream>>>(dst, cnt, E);
    scan_blk<<<nb1024, 1024, 0, stream>>>(cnt, rowptr, bsum, N);
    scan_part<<<1, 1024, 0, stream>>>(bsum, nb1024);
    scan_add<<<nb, B, 0, stream>>>(rowptr, bsum, cnt, dinv, fill, N);
    fill_csr<<<eb, B, 0, stream>>>(src, dst, rowptr, fill, dinv, pairs, E);

    const int gb = 1536;  // grid-stride waves over nodes

    // layer 1: h1 = relu( agg(x) @ W1 + b1 )
    gcn_layer<false><<<gb, B, 0, stream>>>(pairs, rowptr, dinv, x, W1, b1, h1,
                                           Wd1, bd1, Wd2, bd2, pred, N);
    // layer 2 + decoder
    gcn_layer<true><<<gb, B, 0, stream>>>(pairs, rowptr, dinv, h1, W2, b2, h1,
                                          Wd1, bd1, Wd2, bd2, pred, N);
}